// Round 7
// baseline (334.351 us; speedup 1.0000x reference)
//
#include <hip/hip_runtime.h>

typedef _Float16 half8_t __attribute__((ext_vector_type(8)));
typedef _Float16 half4_t __attribute__((ext_vector_type(4)));
typedef _Float16 half2_t __attribute__((ext_vector_type(2)));
typedef __fp16 fp16x2 __attribute__((ext_vector_type(2)));
typedef float f32x4 __attribute__((ext_vector_type(4)));

#define S_LEN 2048
#define D_DIM 64
#define SD (S_LEN * D_DIM)
#define LDK 72             // fallback kernel: f16 row stride
#define LDO 68             // f32 row stride for epilogue
#define THR 4.0f           // lazy-max threshold: stale-path P <= 2^4
#define WS_NEED ((size_t)(16 * 1024 * 1024 + 16384))

// ============================================================================
// PREP (once): K -> f16 row-major 8KB tiles (PLAIN layout — main kernel reads
// global directly, banks don't exist, so no swizzle); V -> transposed f16
// tiles with MASKED ROWS ZEROED, k-interleaved so one b128 per lane fetches
// the A-frags of two adjacent 16-key sub-tiles on full 64B lines:
//   byte(d, k=16mt+4g+e) = d*128 + (mt>>1)*64 + g*16 + (mt&1)*8 + e*2
// keep[] -> f16 {0,1} (l-sum MFMA A-operand).
// ============================================================================
__global__ __launch_bounds__(256)
void prep_kernel(const float* __restrict__ Kg, const float* __restrict__ Vg,
                 const int* __restrict__ Mg, _Float16* __restrict__ wsK,
                 _Float16* __restrict__ wsV, _Float16* __restrict__ wsKeep) {
  __shared__ float vt[64][68];
  const int blk = blockIdx.x;   // [0,1024) K; [1024,2048) V; [2048,2052) keep
  const int t = threadIdx.x;

  if (blk < 1024) {
    const int bh = blk >> 5, kt = blk & 31;
    const float* src = Kg + (size_t)bh * SD + (size_t)kt * 64 * D_DIM;
    char* dst = (char*)wsK + (size_t)blk * 8192;
#pragma unroll
    for (int i = 0; i < 2; ++i) {
      int task = t + 256 * i;        // 512 granules: row 0..63 x j 0..7
      int row = task >> 3, j = task & 7;
      float4 lo = *(const float4*)(src + row * D_DIM + 8 * j);
      float4 hi = *(const float4*)(src + row * D_DIM + 8 * j + 4);
      fp16x2 p0 = __builtin_amdgcn_cvt_pkrtz(lo.x, lo.y);
      fp16x2 p1 = __builtin_amdgcn_cvt_pkrtz(lo.z, lo.w);
      fp16x2 p2 = __builtin_amdgcn_cvt_pkrtz(hi.x, hi.y);
      fp16x2 p3 = __builtin_amdgcn_cvt_pkrtz(hi.z, hi.w);
      half8_t h;
      h[0] = (_Float16)p0[0]; h[1] = (_Float16)p0[1];
      h[2] = (_Float16)p1[0]; h[3] = (_Float16)p1[1];
      h[4] = (_Float16)p2[0]; h[5] = (_Float16)p2[1];
      h[6] = (_Float16)p3[0]; h[7] = (_Float16)p3[1];
      *(half8_t*)(dst + row * 128 + 16 * j) = h;
    }
  } else if (blk < 2048) {
    const int vb = blk - 1024;
    const int bh = vb >> 5, kt = vb & 31;
    const float* src = Vg + (size_t)bh * SD + (size_t)kt * 64 * D_DIM;
    const int* msk = Mg + (size_t)(bh >> 3) * S_LEN + kt * 64;
#pragma unroll
    for (int i = 0; i < 4; ++i) {
      int r = (t >> 4) + 16 * i, c4 = t & 15;
      *(float4*)&vt[r][c4 * 4] = *(const float4*)(src + r * D_DIM + c4 * 4);
    }
    __syncthreads();
    char* dst = (char*)wsV + (size_t)vb * 8192;
#pragma unroll
    for (int i = 0; i < 4; ++i) {
      int task = t + 256 * i;        // 1024 granules: drow 0..63 x j2 0..15
      int drow = task >> 4, j2 = task & 15;
      int k0 = 16 * (2 * (j2 >> 3) + (j2 & 1)) + 4 * ((j2 >> 1) & 3);
      int4 mv = *(const int4*)(msk + k0);
      float a  = vt[k0][drow]     * (float)mv.x;
      float b  = vt[k0 + 1][drow] * (float)mv.y;
      float cc = vt[k0 + 2][drow] * (float)mv.z;
      float d  = vt[k0 + 3][drow] * (float)mv.w;
      fp16x2 h0 = __builtin_amdgcn_cvt_pkrtz(a, b);
      fp16x2 h1 = __builtin_amdgcn_cvt_pkrtz(cc, d);
      half4_t h;
      h[0] = (_Float16)h0[0]; h[1] = (_Float16)h0[1];
      h[2] = (_Float16)h1[0]; h[3] = (_Float16)h1[1];
      *(half4_t*)(dst + drow * 128 + 8 * j2) = h;
    }
  } else {
    const int b = blk - 2048;      // batch
    const int* src = Mg + (size_t)b * S_LEN + 8 * t;
    int4 m0 = *(const int4*)src;
    int4 m1 = *(const int4*)(src + 4);
    half8_t h;
    h[0] = (_Float16)(float)m0.x; h[1] = (_Float16)(float)m0.y;
    h[2] = (_Float16)(float)m0.z; h[3] = (_Float16)(float)m0.w;
    h[4] = (_Float16)(float)m1.x; h[5] = (_Float16)(float)m1.y;
    h[6] = (_Float16)(float)m1.z; h[7] = (_Float16)(float)m1.w;
    *(half8_t*)(wsKeep + (size_t)b * S_LEN + 8 * t) = h;
  }
}

// ============================================================================
// MAIN: FREE-RUNNING WAVES. No LDS (except epilogue transpose), no barriers
// in the main loop. Each wave owns 16 q-rows; MFMA fragments are read
// directly from the L2-resident workspace into registers, double-buffered
// one full iteration ahead (ping/pong FragSets, static indexing). Grid 1024
// -> 4 blocks/CU, 4 waves/SIMD; desynchronized waves overlap each other's
// load/VALU/MFMA phases — the overlap barrier-lockstep structures never got.
// Per-iter (32 keys): 4 QK MFMA (16x16x32) + 10 PV/l MFMA (16x16x16) +
// 8 b128 + 2 b64 global loads + ~40 VALU.
// ============================================================================
__global__ __launch_bounds__(256, 4)
void fattn_reg(const float* __restrict__ Qg, const _Float16* __restrict__ wsK,
               const _Float16* __restrict__ wsV,
               const _Float16* __restrict__ wsKeep, float* __restrict__ Og) {
  __shared__ float Osh[64 * LDO];   // 17.4 KB; only the epilogue uses LDS

  const int t = threadIdx.x;
  const int w = t >> 6;
  const int lane = t & 63;
  const int g = lane >> 4;
  const int c = lane & 15;

  const int bh = blockIdx.x & 31;   // bh fast: one bh's ws stays in one XCD L2
  const int qt = blockIdx.x >> 5;
  const int qb = qt * 64;           // 64 q-rows per block (16 per wave)

  const float* Qb = Qg + (size_t)bh * SD;
  float*       Ob = Og + (size_t)bh * SD;

  // ---- Q^T B-frags for q = qb + 16w + c; fold 1/8 * log2(e) ----
  const float qscale = 0.125f * 1.44269504088896340736f;
  half8_t qf0, qf1;
  {
    const float* qp = Qb + (size_t)(qb + 16 * w + c) * D_DIM + 8 * g;
#pragma unroll
    for (int ks = 0; ks < 2; ++ks) {
      float4 lo = *(const float4*)(qp + 32 * ks);
      float4 hi = *(const float4*)(qp + 32 * ks + 4);
      fp16x2 p0 = __builtin_amdgcn_cvt_pkrtz(lo.x * qscale, lo.y * qscale);
      fp16x2 p1 = __builtin_amdgcn_cvt_pkrtz(lo.z * qscale, lo.w * qscale);
      fp16x2 p2 = __builtin_amdgcn_cvt_pkrtz(hi.x * qscale, hi.y * qscale);
      fp16x2 p3 = __builtin_amdgcn_cvt_pkrtz(hi.z * qscale, hi.w * qscale);
      half8_t hh;
      hh[0] = (_Float16)p0[0]; hh[1] = (_Float16)p0[1];
      hh[2] = (_Float16)p1[0]; hh[3] = (_Float16)p1[1];
      hh[4] = (_Float16)p2[0]; hh[5] = (_Float16)p2[1];
      hh[6] = (_Float16)p3[0]; hh[7] = (_Float16)p3[1];
      if (ks == 0) qf0 = hh; else qf1 = hh;
    }
  }

  // ---- per-lane base pointers (imm offsets stay < 4096 by construction) ----
  // kf: (16mt+c)*128 + ks*64 + g*16  -> base c*128+g*16, imm {0,64,2048,2112}
  // vf: (16dt+c)*128 + half*64 + g*16 -> vB0 (dt 0,1), vB1=vB0+4096 (dt 2,3)
  const char* kB  = (const char*)wsK + (size_t)bh * 262144 + (size_t)c * 128 + g * 16;
  const char* vB0 = (const char*)wsV + (size_t)bh * 262144 + (size_t)c * 128 + g * 16;
  const char* vB1 = vB0 + 4096;
  const _Float16* kpB = wsKeep + (size_t)(bh >> 3) * S_LEN + 4 * g;

  struct FragSet {
    half8_t kf00, kf01, kf10, kf11;  // K A-frags [mt][ks]
    half8_t vf0, vf1, vf2, vf3;      // V A-frag pairs per dt (mt even|odd)
    half4_t kA0, kA1;                // keep A-frags per mt
  };

  auto loadSet = [&](FragSet& S, const char* kp, const char* v0,
                     const char* v1, const _Float16* kpp, int ho)
      __attribute__((always_inline)) {
    S.kf00 = *(const half8_t*)(kp);
    S.kf01 = *(const half8_t*)(kp + 64);
    S.kf10 = *(const half8_t*)(kp + 2048);
    S.kf11 = *(const half8_t*)(kp + 2112);
    S.vf0 = *(const half8_t*)(v0 + ho);
    S.vf1 = *(const half8_t*)(v0 + 2048 + ho);
    S.vf2 = *(const half8_t*)(v1 + ho);
    S.vf3 = *(const half8_t*)(v1 + 2048 + ho);
    S.kA0 = *(const half4_t*)(kpp);
    S.kA1 = *(const half4_t*)(kpp + 16);
  };

  f32x4 acc0 = {0.f,0.f,0.f,0.f}, acc1 = {0.f,0.f,0.f,0.f};
  f32x4 acc2 = {0.f,0.f,0.f,0.f}, acc3 = {0.f,0.f,0.f,0.f};
  f32x4 accl = {0.f,0.f,0.f,0.f};
  float mrun = -1e30f;

  auto compute = [&](FragSet& S) __attribute__((always_inline)) {
    // QK: S^T for 32 keys (2 sub-tiles)
    __builtin_amdgcn_s_setprio(1);
    f32x4 s0 = {0.f,0.f,0.f,0.f}, s1 = {0.f,0.f,0.f,0.f};
    s0 = __builtin_amdgcn_mfma_f32_16x16x32_f16(S.kf00, qf0, s0, 0, 0, 0);
    s0 = __builtin_amdgcn_mfma_f32_16x16x32_f16(S.kf01, qf1, s0, 0, 0, 0);
    s1 = __builtin_amdgcn_mfma_f32_16x16x32_f16(S.kf10, qf0, s1, 0, 0, 0);
    s1 = __builtin_amdgcn_mfma_f32_16x16x32_f16(S.kf11, qf1, s1, 0, 0, 0);
    __builtin_amdgcn_s_setprio(0);

    // lazy raw-score max (no cross-lane in common path)
    float tl = fmaxf(fmaxf(fmaxf(s0[0], s0[1]), fmaxf(s0[2], s0[3])),
                     fmaxf(fmaxf(s1[0], s1[1]), fmaxf(s1[2], s1[3])));
    if (!__all(tl <= mrun + THR)) {
      float tmax = fmaxf(tl, __shfl_xor(tl, 16));
      tmax = fmaxf(tmax, __shfl_xor(tmax, 32));
      float mnew = fmaxf(mrun, tmax);
      float alpha = __builtin_amdgcn_exp2f(mrun - mnew);
      mrun = mnew;
#pragma unroll
      for (int r = 0; r < 4; ++r) {
        accl[r] *= alpha;
        acc0[r] *= alpha; acc1[r] *= alpha;
        acc2[r] *= alpha; acc3[r] *= alpha;
      }
    }

    // exp + in-register pack: P B-frags (QK C-layout == PV B-frag layout)
    float p00 = __builtin_amdgcn_exp2f(s0[0] - mrun);
    float p01 = __builtin_amdgcn_exp2f(s0[1] - mrun);
    float p02 = __builtin_amdgcn_exp2f(s0[2] - mrun);
    float p03 = __builtin_amdgcn_exp2f(s0[3] - mrun);
    float p10 = __builtin_amdgcn_exp2f(s1[0] - mrun);
    float p11 = __builtin_amdgcn_exp2f(s1[1] - mrun);
    float p12 = __builtin_amdgcn_exp2f(s1[2] - mrun);
    float p13 = __builtin_amdgcn_exp2f(s1[3] - mrun);
    fp16x2 a0 = __builtin_amdgcn_cvt_pkrtz(p00, p01);
    fp16x2 a1 = __builtin_amdgcn_cvt_pkrtz(p02, p03);
    fp16x2 b0 = __builtin_amdgcn_cvt_pkrtz(p10, p11);
    fp16x2 b1 = __builtin_amdgcn_cvt_pkrtz(p12, p13);
    half4_t pf0, pf1;
    pf0[0] = (_Float16)a0[0]; pf0[1] = (_Float16)a0[1];
    pf0[2] = (_Float16)a1[0]; pf0[3] = (_Float16)a1[1];
    pf1[0] = (_Float16)b0[0]; pf1[1] = (_Float16)b0[1];
    pf1[2] = (_Float16)b1[0]; pf1[3] = (_Float16)b1[1];

    // PV + l-sum (keep-MFMA)
    __builtin_amdgcn_s_setprio(1);
    accl = __builtin_amdgcn_mfma_f32_16x16x16f16(S.kA0, pf0, accl, 0, 0, 0);
    accl = __builtin_amdgcn_mfma_f32_16x16x16f16(S.kA1, pf1, accl, 0, 0, 0);
    half4_t v;
    v = __builtin_shufflevector(S.vf0, S.vf0, 0, 1, 2, 3);
    acc0 = __builtin_amdgcn_mfma_f32_16x16x16f16(v, pf0, acc0, 0, 0, 0);
    v = __builtin_shufflevector(S.vf0, S.vf0, 4, 5, 6, 7);
    acc0 = __builtin_amdgcn_mfma_f32_16x16x16f16(v, pf1, acc0, 0, 0, 0);
    v = __builtin_shufflevector(S.vf1, S.vf1, 0, 1, 2, 3);
    acc1 = __builtin_amdgcn_mfma_f32_16x16x16f16(v, pf0, acc1, 0, 0, 0);
    v = __builtin_shufflevector(S.vf1, S.vf1, 4, 5, 6, 7);
    acc1 = __builtin_amdgcn_mfma_f32_16x16x16f16(v, pf1, acc1, 0, 0, 0);
    v = __builtin_shufflevector(S.vf2, S.vf2, 0, 1, 2, 3);
    acc2 = __builtin_amdgcn_mfma_f32_16x16x16f16(v, pf0, acc2, 0, 0, 0);
    v = __builtin_shufflevector(S.vf2, S.vf2, 4, 5, 6, 7);
    acc2 = __builtin_amdgcn_mfma_f32_16x16x16f16(v, pf1, acc2, 0, 0, 0);
    v = __builtin_shufflevector(S.vf3, S.vf3, 0, 1, 2, 3);
    acc3 = __builtin_amdgcn_mfma_f32_16x16x16f16(v, pf0, acc3, 0, 0, 0);
    v = __builtin_shufflevector(S.vf3, S.vf3, 4, 5, 6, 7);
    acc3 = __builtin_amdgcn_mfma_f32_16x16x16f16(v, pf1, acc3, 0, 0, 0);
    __builtin_amdgcn_s_setprio(0);
  };

  // ---- main loop: 64 x 32-key steps, ping/pong frag sets, prefetch d=1 ----
  FragSet A, B;
  loadSet(A, kB, vB0, vB1, kpB, 0);
  kB += 4096; kpB += 32;
  for (int tt = 0; tt < 62; tt += 2) {
    loadSet(B, kB, vB0, vB1, kpB, 64);        // odd half of current V tile
    kB += 4096; kpB += 32; vB0 += 8192; vB1 += 8192;
    compute(A);
    loadSet(A, kB, vB0, vB1, kpB, 0);         // even half of next V tile
    kB += 4096; kpB += 32;
    compute(B);
  }
  loadSet(B, kB, vB0, vB1, kpB, 64);
  compute(A);
  compute(B);

  // ---- epilogue: /l, transpose O^T -> O via LDS, coalesced stores ----
  {
    float linv = 1.f / accl[0];   // keep-MFMA replicates l over rows
    int row = (16 * w + c) * LDO + 4 * g;
#pragma unroll
    for (int r = 0; r < 4; ++r) {
      Osh[row + 0  + r] = acc0[r] * linv;
      Osh[row + 16 + r] = acc1[r] * linv;
      Osh[row + 32 + r] = acc2[r] * linv;
      Osh[row + 48 + r] = acc3[r] * linv;
    }
  }
  __syncthreads();
  {
    int f8 = t & 7;
#pragma unroll
    for (int i = 0; i < 2; ++i) {
      int q = (t >> 3) + 32 * i;
#pragma unroll
      for (int j = 0; j < 2; ++j) {
        int c4 = f8 + 8 * j;
        f32x4 o = *(f32x4*)(Osh + q * LDO + c4 * 4);
        *(float4*)(Ob + (size_t)(qb + q) * D_DIM + c4 * 4) =
            make_float4(o.x, o.y, o.z, o.w);
      }
    }
  }
}

// ============================================================================
// FALLBACK (round-3 kernel) — used only if ws_size < WS_NEED.
// ============================================================================
__global__ __launch_bounds__(256, 2)
void fattn_fb(const float* __restrict__ Qg, const float* __restrict__ Kg,
              const float* __restrict__ Vg, const int* __restrict__ Mg,
              float* __restrict__ Og) {
  __shared__ __align__(16) char smem[45056];
  float* Msh = (float*)(smem + 36864);
  float* Osh = (float*)smem;

  const int t = threadIdx.x;
  const int w = t >> 6;
  const int lane = t & 63;
  const int g = lane >> 4;
  const int c = lane & 15;

  const int bh = blockIdx.x & 31;
  const int qt = blockIdx.x >> 5;
  const int qb = qt * 128;

  const float* Qb = Qg + (size_t)bh * SD;
  const float* Kb = Kg + (size_t)bh * SD;
  const float* Vb = Vg + (size_t)bh * SD;
  const int*   Mb = Mg + (size_t)(bh >> 3) * S_LEN;
  float*       Ob = Og + (size_t)bh * SD;

  {
    int4 m0 = *(const int4*)(Mb + 8 * t);
    int4 m1 = *(const int4*)(Mb + 8 * t + 4);
    float4 f0, f1;
    f0.x = (float)(m0.x - 1) * 1e30f; f0.y = (float)(m0.y - 1) * 1e30f;
    f0.z = (float)(m0.z - 1) * 1e30f; f0.w = (float)(m0.w - 1) * 1e30f;
    f1.x = (float)(m1.x - 1) * 1e30f; f1.y = (float)(m1.y - 1) * 1e30f;
    f1.z = (float)(m1.z - 1) * 1e30f; f1.w = (float)(m1.w - 1) * 1e30f;
    *(float4*)(Msh + 8 * t) = f0;
    *(float4*)(Msh + 8 * t + 4) = f1;
  }

  const float qscale = 0.125f * 1.44269504088896340736f;
  half8_t qf[2][2];
#pragma unroll
  for (int h = 0; h < 2; ++h) {
    const float* qp = Qb + (size_t)(qb + 32 * w + 16 * h + c) * D_DIM + 8 * g;
#pragma unroll
    for (int ks = 0; ks < 2; ++ks) {
      float4 lo = *(const float4*)(qp + 32 * ks);
      float4 hi = *(const float4*)(qp + 32 * ks + 4);
      fp16x2 p0 = __builtin_amdgcn_cvt_pkrtz(lo.x * qscale, lo.y * qscale);
      fp16x2 p1 = __builtin_amdgcn_cvt_pkrtz(lo.z * qscale, lo.w * qscale);
      fp16x2 p2 = __builtin_amdgcn_cvt_pkrtz(hi.x * qscale, hi.y * qscale);
      fp16x2 p3 = __builtin_amdgcn_cvt_pkrtz(hi.z * qscale, hi.w * qscale);
      half8_t hh;
      hh[0] = (_Float16)p0[0]; hh[1] = (_Float16)p0[1];
      hh[2] = (_Float16)p1[0]; hh[3] = (_Float16)p1[1];
      hh[4] = (_Float16)p2[0]; hh[5] = (_Float16)p2[1];
      hh[6] = (_Float16)p3[0]; hh[7] = (_Float16)p3[1];
      qf[h][ks] = hh;
    }
  }

  const int krow0 = t >> 4;
  const int kc4   = t & 15;
  const int vp    = t >> 3;
  const int vkpl  = t & 7;

  float4 kr[4];
  float2 vr[8];
  auto prefetch = [&](int kb2) {
#pragma unroll
    for (int it = 0; it < 4; ++it)
      kr[it] = *(const float4*)(Kb + (size_t)(kb2 + krow0 + 16 * it) * D_DIM + kc4 * 4);
#pragma unroll
    for (int kc = 0; kc < 4; ++kc) {
      const float* vpp = Vb + (size_t)(kb2 + 2 * (vkpl + 8 * kc)) * D_DIM + 2 * vp;
      vr[2 * kc]     = *(const float2*)(vpp);
      vr[2 * kc + 1] = *(const float2*)(vpp + D_DIM);
    }
  };
  auto stage = [&](int buf) {
    _Float16* Kd = (_Float16*)(smem + 9216 * buf);
    _Float16* Vd = (_Float16*)(smem + 18432 + 9216 * buf);
#pragma unroll
    for (int it = 0; it < 4; ++it) {
      fp16x2 a  = __builtin_amdgcn_cvt_pkrtz(kr[it].x, kr[it].y);
      fp16x2 b2 = __builtin_amdgcn_cvt_pkrtz(kr[it].z, kr[it].w);
      half4_t h;
      h[0] = (_Float16)a[0]; h[1] = (_Float16)a[1];
      h[2] = (_Float16)b2[0]; h[3] = (_Float16)b2[1];
      *(half4_t*)(Kd + (krow0 + 16 * it) * LDK + kc4 * 4) = h;
    }
#pragma unroll
    for (int kc = 0; kc < 4; ++kc) {
      int kp = vkpl + 8 * kc;
      fp16x2 h0 = __builtin_amdgcn_cvt_pkrtz(vr[2 * kc].x, vr[2 * kc + 1].x);
      fp16x2 h1 = __builtin_amdgcn_cvt_pkrtz(vr[2 * kc].y, vr[2 * kc + 1].y);
      half2_t g0; g0[0] = (_Float16)h0[0]; g0[1] = (_Float16)h0[1];
      half2_t g1; g1[0] = (_Float16)h1[0]; g1[1] = (_Float16)h1[1];
      *(half2_t*)(Vd + (2 * vp) * LDK + 2 * kp) = g0;
      *(half2_t*)(Vd + (2 * vp + 1) * LDK + 2 * kp) = g1;
    }
  };

  f32x4 acc[2][4];
  f32x4 accl[2];
#pragma unroll
  for (int h = 0; h < 2; ++h) {
#pragma unroll
    for (int j = 0; j < 4; ++j) accl[h][j] = 0.f;
#pragma unroll
    for (int i = 0; i < 4; ++i)
#pragma unroll
      for (int j = 0; j < 4; ++j) acc[h][i][j] = 0.f;
  }
  float mrun[2] = {-1e30f, -1e30f};

  half4_t ones4;
  ones4[0] = (_Float16)1.0f; ones4[1] = (_Float16)1.0f;
  ones4[2] = (_Float16)1.0f; ones4[3] = (_Float16)1.0f;

  prefetch(0);
  stage(0);
  prefetch(64);
  __syncthreads();

  for (int kt = 0; kt < 32; ++kt) {
    const int kb = kt * 64;
    const int cur = kt & 1;

    if (kt < 31) stage(cur ^ 1);
    if (kt < 30) prefetch(kb + 128);

    const _Float16* Kc = (const _Float16*)(smem + 9216 * cur);
    const _Float16* Vc = (const _Float16*)(smem + 18432 + 9216 * cur);

    f32x4 sT[2][4];
    __builtin_amdgcn_s_setprio(1);
#pragma unroll
    for (int mt = 0; mt < 4; ++mt) {
      f32x4 z0, z1;
#pragma unroll
      for (int j = 0; j < 4; ++j) { z0[j] = 0.f; z1[j] = 0.f; }
#pragma unroll
      for (int ks = 0; ks < 2; ++ks) {
        half8_t kf = *(half8_t*)(Kc + (16 * mt + c) * LDK + ks * 32 + 8 * g);
        z0 = __builtin_amdgcn_mfma_f32_16x16x32_f16(kf, qf[0][ks], z0, 0, 0, 0);
        z1 = __builtin_amdgcn_mfma_f32_16x16x32_f16(kf, qf[1][ks], z1, 0, 0, 0);
      }
      sT[0][mt] = z0;
      sT[1][mt] = z1;
    }
    __builtin_amdgcn_s_setprio(0);

    half4_t vf[4][4];
#pragma unroll
    for (int dt = 0; dt < 4; ++dt)
#pragma unroll
      for (int kst = 0; kst < 4; ++kst)
        vf[dt][kst] = *(half4_t*)(Vc + (16 * dt + c) * LDK + 16 * kst + 4 * g);

    f32x4 mvf[4];
#pragma unroll
    for (int mt = 0; mt < 4; ++mt)
      mvf[mt] = *(const f32x4*)(Msh + kb + 16 * mt + 4 * g);
#pragma unroll
    for (int h = 0; h < 2; ++h)
#pragma unroll
      for (int mt = 0; mt < 4; ++mt)
#pragma unroll
        for (int r = 0; r < 4; ++r) sT[h][mt][r] += mvf[mt][r];

    float tl[2];
#pragma unroll
    for (int h = 0; h < 2; ++h) {
      float tm0 = fmaxf(fmaxf(sT[h][0][0], sT[h][0][1]),
                        fmaxf(sT[h][0][2], sT[h][0][3]));
      float tm1 = fmaxf(fmaxf(sT[h][1][0], sT[h][1][1]),
                        fmaxf(sT[h][1][2], sT[h][1][3]));
      float tm2 = fmaxf(fmaxf(sT[h][2][0], sT[h][2][1]),
                        fmaxf(sT[h][2][2], sT[h][2][3]));
      float tm3 = fmaxf(fmaxf(sT[h][3][0], sT[h][3][1]),
                        fmaxf(sT[h][3][2], sT[h][3][3]));
      tl[h] = fmaxf(fmaxf(tm0, tm1), fmaxf(tm2, tm3));
    }
    int ok0 = __all(tl[0] <= mrun[0] + THR);
    int ok1 = __all(tl[1] <= mrun[1] + THR);
    if (!(ok0 & ok1)) {
#pragma unroll
      for (int h = 0; h < 2; ++h) {
        float tmax = tl[h];
        tmax = fmaxf(tmax, __shfl_xor(tmax, 16));
        tmax = fmaxf(tmax, __shfl_xor(tmax, 32));
        float mnew = fmaxf(mrun[h], tmax);
        float alpha = __builtin_amdgcn_exp2f(mrun[h] - mnew);
        mrun[h] = mnew;
        accl[h][0] *= alpha; accl[h][1] *= alpha;
        accl[h][2] *= alpha; accl[h][3] *= alpha;
#pragma unroll
        for (int mt = 0; mt < 4; ++mt) {
          acc[h][mt][0] *= alpha; acc[h][mt][1] *= alpha;
          acc[h][mt][2] *= alpha; acc[h][mt][3] *= alpha;
        }
      }
    }

    __builtin_amdgcn_s_setprio(1);
#pragma unroll
    for (int h = 0; h < 2; ++h) {
#pragma unroll
      for (int mt = 0; mt < 4; ++mt) {
        float pv0 = __builtin_amdgcn_exp2f(sT[h][mt][0] - mrun[h]);
        float pv1 = __builtin_amdgcn_exp2f(sT[h][mt][1] - mrun[h]);
        float pv2 = __builtin_amdgcn_exp2f(sT[h][mt][2] - mrun[h]);
        float pv3 = __builtin_amdgcn_exp2f(sT[h][mt][3] - mrun[h]);
        fp16x2 p01 = __builtin_amdgcn_cvt_pkrtz(pv0, pv1);
        fp16x2 p23 = __builtin_amdgcn_cvt_pkrtz(pv2, pv3);
        half4_t pf;
        pf[0] = (_Float16)p01[0]; pf[1] = (_Float16)p01[1];
        pf[2] = (_Float16)p23[0]; pf[3] = (_Float16)p23[1];
        accl[h] = __builtin_amdgcn_mfma_f32_16x16x16f16(ones4, pf, accl[h], 0, 0, 0);
#pragma unroll
        for (int dt = 0; dt < 4; ++dt)
          acc[h][dt] = __builtin_amdgcn_mfma_f32_16x16x16f16(vf[dt][mt], pf,
                                                             acc[h][dt], 0, 0, 0);
      }
    }
    __builtin_amdgcn_s_setprio(0);

    __syncthreads();
  }

#pragma unroll
  for (int h = 0; h < 2; ++h) {
    float linv = 1.f / accl[h][0];
#pragma unroll
    for (int mt = 0; mt < 4; ++mt)
#pragma unroll
      for (int r = 0; r < 4; ++r)
        Osh[(32 * w + 16 * h + c) * LDO + 16 * mt + 4 * g + r] = acc[h][mt][r] * linv;
  }
  __syncthreads();
  {
    int f8 = t & 7;
#pragma unroll
    for (int i = 0; i < 4; ++i) {
      int q = (t >> 3) + 32 * i;
#pragma unroll
      for (int j = 0; j < 2; ++j) {
        int c4 = f8 + 8 * j;
        f32x4 o = *(f32x4*)(Osh + q * LDO + c4 * 4);
        *(float4*)(Ob + (size_t)(qb + q) * D_DIM + c4 * 4) =
            make_float4(o.x, o.y, o.z, o.w);
      }
    }
  }
}

extern "C" void kernel_launch(void* const* d_in, const int* in_sizes, int n_in,
                              void* d_out, int out_size, void* d_ws, size_t ws_size,
                              hipStream_t stream) {
  (void)in_sizes; (void)n_in; (void)out_size;
  const float* Q = (const float*)d_in[0];
  const float* K = (const float*)d_in[1];
  const float* V = (const float*)d_in[2];
  const int*   M = (const int*)d_in[3];
  float* O = (float*)d_out;

  if (ws_size >= WS_NEED && d_ws != nullptr) {
    _Float16* wsK = (_Float16*)d_ws;
    _Float16* wsV = wsK + (size_t)32 * S_LEN * D_DIM;               // +8MB
    _Float16* wsKeep = (_Float16*)((char*)d_ws + 16 * 1024 * 1024); // +16MB
    prep_kernel<<<dim3(2052), dim3(256), 0, stream>>>(K, V, M, wsK, wsV, wsKeep);
    // grid 1024: bh fast (XCD L2 locality), 32 q-tiles of 64 rows slow
    fattn_reg<<<dim3(32 * 32), dim3(256), 0, stream>>>(Q, wsK, wsV, wsKeep, O);
  } else {
    fattn_fb<<<dim3(32 * 16), dim3(256), 0, stream>>>(Q, K, V, M, O);
  }
}

// Round 8
// 147.588 us; speedup vs baseline: 2.2654x; 2.2654x over previous
//
#include <hip/hip_runtime.h>

typedef _Float16 half8_t __attribute__((ext_vector_type(8)));
typedef _Float16 half4_t __attribute__((ext_vector_type(4)));
typedef _Float16 half2_t __attribute__((ext_vector_type(2)));
typedef __fp16 fp16x2 __attribute__((ext_vector_type(2)));
typedef float f32x4 __attribute__((ext_vector_type(4)));

#define S_LEN 2048
#define D_DIM 64
#define SD (S_LEN * D_DIM)
#define LDK 72             // fallback kernel: f16 row stride
#define LDO 68             // f32 row stride for epilogue
#define THR 4.0f           // lazy-max threshold: stale-path P <= 2^4
#define WS_NEED ((size_t)(16 * 1024 * 1024 + 16384))

// ============================================================================
// PREP (once; round-6 version, proven): K -> swizzled f16 8KB tiles; V ->
// transposed, swizzled f16 8KB tiles with MASKED ROWS ZEROED; keep[] -> f16.
// K tile: byte(row,16B-gran j) = row*128 + ((16j) ^ ((row&7)<<4))
// V tile: byte(drow,8B-gran j2) = drow*128 + ((8j2) ^ ((drow&15)<<3))
// ============================================================================
__global__ __launch_bounds__(256)
void prep_kernel(const float* __restrict__ Kg, const float* __restrict__ Vg,
                 const int* __restrict__ Mg, _Float16* __restrict__ wsK,
                 _Float16* __restrict__ wsV, _Float16* __restrict__ wsKeep) {
  __shared__ float vt[64][68];
  const int blk = blockIdx.x;   // [0,1024) K; [1024,2048) V; [2048,2052) keep
  const int t = threadIdx.x;

  if (blk < 1024) {
    const int bh = blk >> 5, kt = blk & 31;
    const float* src = Kg + (size_t)bh * SD + (size_t)kt * 64 * D_DIM;
    char* dst = (char*)wsK + (size_t)blk * 8192;
#pragma unroll
    for (int i = 0; i < 2; ++i) {
      int task = t + 256 * i;        // 512 granules: row 0..63 x j 0..7
      int row = task >> 3, j = task & 7;
      float4 lo = *(const float4*)(src + row * D_DIM + 8 * j);
      float4 hi = *(const float4*)(src + row * D_DIM + 8 * j + 4);
      fp16x2 p0 = __builtin_amdgcn_cvt_pkrtz(lo.x, lo.y);
      fp16x2 p1 = __builtin_amdgcn_cvt_pkrtz(lo.z, lo.w);
      fp16x2 p2 = __builtin_amdgcn_cvt_pkrtz(hi.x, hi.y);
      fp16x2 p3 = __builtin_amdgcn_cvt_pkrtz(hi.z, hi.w);
      half8_t h;
      h[0] = (_Float16)p0[0]; h[1] = (_Float16)p0[1];
      h[2] = (_Float16)p1[0]; h[3] = (_Float16)p1[1];
      h[4] = (_Float16)p2[0]; h[5] = (_Float16)p2[1];
      h[6] = (_Float16)p3[0]; h[7] = (_Float16)p3[1];
      *(half8_t*)(dst + row * 128 + ((16 * j) ^ ((row & 7) << 4))) = h;
    }
  } else if (blk < 2048) {
    const int vb = blk - 1024;
    const int bh = vb >> 5, kt = vb & 31;
    const float* src = Vg + (size_t)bh * SD + (size_t)kt * 64 * D_DIM;
    const int* msk = Mg + (size_t)(bh >> 3) * S_LEN + kt * 64;
#pragma unroll
    for (int i = 0; i < 4; ++i) {
      int r = (t >> 4) + 16 * i, c4 = t & 15;
      *(float4*)&vt[r][c4 * 4] = *(const float4*)(src + r * D_DIM + c4 * 4);
    }
    __syncthreads();
    char* dst = (char*)wsV + (size_t)vb * 8192;
#pragma unroll
    for (int i = 0; i < 4; ++i) {
      int task = t + 256 * i;        // 1024 granules: drow 0..63 x j2 0..15
      int drow = task >> 4, j2 = task & 15, k0 = 4 * j2;
      int4 mv = *(const int4*)(msk + k0);
      float a  = vt[k0][drow]     * (float)mv.x;
      float b  = vt[k0 + 1][drow] * (float)mv.y;
      float cc = vt[k0 + 2][drow] * (float)mv.z;
      float d  = vt[k0 + 3][drow] * (float)mv.w;
      fp16x2 h0 = __builtin_amdgcn_cvt_pkrtz(a, b);
      fp16x2 h1 = __builtin_amdgcn_cvt_pkrtz(cc, d);
      half4_t h;
      h[0] = (_Float16)h0[0]; h[1] = (_Float16)h0[1];
      h[2] = (_Float16)h1[0]; h[3] = (_Float16)h1[1];
      *(half4_t*)(dst + drow * 128 + ((8 * j2) ^ ((drow & 15) << 3))) = h;
    }
  } else {
    const int b = blk - 2048;      // batch
    const int* src = Mg + (size_t)b * S_LEN + 8 * t;
    int4 m0 = *(const int4*)src;
    int4 m1 = *(const int4*)(src + 4);
    half8_t h;
    h[0] = (_Float16)(float)m0.x; h[1] = (_Float16)(float)m0.y;
    h[2] = (_Float16)(float)m0.z; h[3] = (_Float16)(float)m0.w;
    h[4] = (_Float16)(float)m1.x; h[5] = (_Float16)(float)m1.y;
    h[6] = (_Float16)(float)m1.z; h[7] = (_Float16)(float)m1.w;
    *(half8_t*)(wsKeep + (size_t)b * S_LEN + 8 * t) = h;
  }
}

// ============================================================================
// MAIN: round-5 iteration body (proven 61.4us), block shrunk to 64 q-rows
// (16 q/wave, no h-loop) and grid doubled to 1024 -> 4 INDEPENDENT 4-wave
// blocks per CU (LDS 32KB x 4 = 128KB). History: R0->R1 added waves without
// adding independent convoy units (null); R5's 2 desynced blocks/CU is the
// only overlap we have; R7 proved per-lane global frag reads die on address
// divergence (global_load_lds is load-bearing). This round doubles the
// number of phase-shifted convoys per CU with the iteration body unchanged.
// ============================================================================
__global__ __launch_bounds__(256, 4)
void fattn_dma(const float* __restrict__ Qg, const _Float16* __restrict__ wsK,
               const _Float16* __restrict__ wsV,
               const _Float16* __restrict__ wsKeep, float* __restrict__ Og) {
  __shared__ __align__(16) char smem[32768];
  // K dbuf 2x8192 [0,16384); V dbuf 2x8192 [16384,32768)
  float* Osh = (float*)smem;   // epilogue reuse (17408B)

  const int t = threadIdx.x;
  const int w = t >> 6;
  const int lane = t & 63;
  const int g = lane >> 4;
  const int c = lane & 15;

  const int bh = blockIdx.x & 31;   // bh fast: ws pinned to one XCD's L2
  const int qt = blockIdx.x >> 5;
  const int qb = qt * 64;           // 64 q-rows per block, 16 per wave

  const float* Qb = Qg + (size_t)bh * SD;
  float*       Ob = Og + (size_t)bh * SD;
  const _Float16* keepB = wsKeep + (size_t)(bh >> 3) * S_LEN;  // H = 8

  // ---- Q^T B-frags for q = qb + 16w + c; fold 1/8 * log2(e) ----
  const float qscale = 0.125f * 1.44269504088896340736f;
  half8_t qf[2];
  {
    const float* qp = Qb + (size_t)(qb + 16 * w + c) * D_DIM + 8 * g;
#pragma unroll
    for (int ks = 0; ks < 2; ++ks) {
      float4 lo = *(const float4*)(qp + 32 * ks);
      float4 hi = *(const float4*)(qp + 32 * ks + 4);
      fp16x2 p0 = __builtin_amdgcn_cvt_pkrtz(lo.x * qscale, lo.y * qscale);
      fp16x2 p1 = __builtin_amdgcn_cvt_pkrtz(lo.z * qscale, lo.w * qscale);
      fp16x2 p2 = __builtin_amdgcn_cvt_pkrtz(hi.x * qscale, hi.y * qscale);
      fp16x2 p3 = __builtin_amdgcn_cvt_pkrtz(hi.z * qscale, hi.w * qscale);
      half8_t hh;
      hh[0] = (_Float16)p0[0]; hh[1] = (_Float16)p0[1];
      hh[2] = (_Float16)p1[0]; hh[3] = (_Float16)p1[1];
      hh[4] = (_Float16)p2[0]; hh[5] = (_Float16)p2[1];
      hh[6] = (_Float16)p3[0]; hh[7] = (_Float16)p3[1];
      qf[ks] = hh;
    }
  }

  // ---- DMA staging: per wave 2KB K + 2KB V (4 x 16B/lane issues) ----
  const size_t tbase = (size_t)bh * 262144;
  auto dma = [&](int buf, int kt) {
    const char* gK = (const char*)wsK + tbase + (size_t)kt * 8192 +
                     w * 2048 + lane * 16;
    const char* gV = (const char*)wsV + tbase + (size_t)kt * 8192 +
                     w * 2048 + lane * 16;
    char* lK = smem + 8192 * buf + w * 2048;
    char* lV = smem + 16384 + 8192 * buf + w * 2048;
    __builtin_amdgcn_global_load_lds((const float*)gK, (float*)lK, 16, 0, 0);
    __builtin_amdgcn_global_load_lds((const float*)(gK + 1024),
                                     (float*)(lK + 1024), 16, 0, 0);
    __builtin_amdgcn_global_load_lds((const float*)gV, (float*)lV, 16, 0, 0);
    __builtin_amdgcn_global_load_lds((const float*)(gV + 1024),
                                     (float*)(lV + 1024), 16, 0, 0);
  };

  f32x4 acc[4];
  f32x4 accl;
#pragma unroll
  for (int j = 0; j < 4; ++j) {
    accl[j] = 0.f;
#pragma unroll
    for (int i = 0; i < 4; ++i) acc[i][j] = 0.f;
  }
  float mrun = -1e30f;

  const int kxor = (c & 7) << 4;
  const int vxor = c << 3;

  dma(0, 0);
  __syncthreads();   // tile 0 resident

  for (int kt = 0; kt < 32; ++kt) {
    const int cur = kt & 1;
    if (kt < 31) dma(cur ^ 1, kt + 1);   // next tile in flight under compute

    const char* Kc = smem + 8192 * cur;
    const char* Vc = smem + 16384 + 8192 * cur;

    // ---- keep A-frags for the l-MFMA (global b64, L2-hot, issued early) ----
    half4_t kA[4];
#pragma unroll
    for (int mt = 0; mt < 4; ++mt)
      kA[mt] = *(const half4_t*)(keepB + kt * 64 + 16 * mt + 4 * g);

    // ---- S^T = K . Q^T ----
    f32x4 sT[4];
    __builtin_amdgcn_s_setprio(1);
#pragma unroll
    for (int mt = 0; mt < 4; ++mt) {
      const char* Krow = Kc + (16 * mt + c) * 128;
      f32x4 z;
#pragma unroll
      for (int j = 0; j < 4; ++j) z[j] = 0.f;
#pragma unroll
      for (int ks = 0; ks < 2; ++ks) {
        half8_t kf = *(const half8_t*)(Krow + ((ks * 64 + g * 16) ^ kxor));
        z = __builtin_amdgcn_mfma_f32_16x16x32_f16(kf, qf[ks], z, 0, 0, 0);
      }
      sT[mt] = z;
    }
    __builtin_amdgcn_s_setprio(0);

    // ---- V A-frags (K=16 PV), issued before softmax to hide LDS latency ----
    half4_t vf[4][4];  // [d-tile][k-step]
#pragma unroll
    for (int dt = 0; dt < 4; ++dt)
#pragma unroll
      for (int mtk = 0; mtk < 4; ++mtk)
        vf[dt][mtk] = *(const half4_t*)(Vc + (16 * dt + c) * 128 +
                                        ((32 * mtk + 8 * g) ^ vxor));

    // ---- lazy raw-score max: no cross-lane in the common path ----
    float tl = -1e30f;
#pragma unroll
    for (int mt = 0; mt < 4; ++mt)
      tl = fmaxf(tl, fmaxf(fmaxf(sT[mt][0], sT[mt][1]),
                           fmaxf(sT[mt][2], sT[mt][3])));
    if (!__all(tl <= mrun + THR)) {
      // rare: exact row-max update + alpha rescale (wave-uniform branch)
      float tmax = fmaxf(tl, __shfl_xor(tl, 16));
      tmax = fmaxf(tmax, __shfl_xor(tmax, 32));
      float mnew = fmaxf(mrun, tmax);
      float alpha = __builtin_amdgcn_exp2f(mrun - mnew);
      mrun = mnew;
#pragma unroll
      for (int j = 0; j < 4; ++j) {
        accl[j] *= alpha;
#pragma unroll
        for (int i = 0; i < 4; ++i) acc[i][j] *= alpha;
      }
    }

    // ---- exp + in-register pack + PV; l-sum via keep-MFMA ----
    __builtin_amdgcn_s_setprio(1);
#pragma unroll
    for (int mt = 0; mt < 4; ++mt) {
      float pv0 = __builtin_amdgcn_exp2f(sT[mt][0] - mrun);
      float pv1 = __builtin_amdgcn_exp2f(sT[mt][1] - mrun);
      float pv2 = __builtin_amdgcn_exp2f(sT[mt][2] - mrun);
      float pv3 = __builtin_amdgcn_exp2f(sT[mt][3] - mrun);
      fp16x2 p01 = __builtin_amdgcn_cvt_pkrtz(pv0, pv1);
      fp16x2 p23 = __builtin_amdgcn_cvt_pkrtz(pv2, pv3);
      half4_t pf;
      pf[0] = (_Float16)p01[0]; pf[1] = (_Float16)p01[1];
      pf[2] = (_Float16)p23[0]; pf[3] = (_Float16)p23[1];
      accl = __builtin_amdgcn_mfma_f32_16x16x16f16(kA[mt], pf, accl, 0, 0, 0);
#pragma unroll
      for (int dt = 0; dt < 4; ++dt)
        acc[dt] = __builtin_amdgcn_mfma_f32_16x16x16f16(vf[dt][mt], pf,
                                                        acc[dt], 0, 0, 0);
    }
    __builtin_amdgcn_s_setprio(0);

    __syncthreads();  // drains vmcnt (DMA kt+1 done) + lgkm; guards swap
  }

  // ---- epilogue: /l, transpose O^T -> O via LDS, coalesced stores ----
  {
    float linv = 1.f / accl[0];   // keep-MFMA replicates l over rows
#pragma unroll
    for (int mt = 0; mt < 4; ++mt)
#pragma unroll
      for (int r = 0; r < 4; ++r)
        Osh[(16 * w + c) * LDO + 16 * mt + 4 * g + r] = acc[mt][r] * linv;
  }
  __syncthreads();
  {
    int f8 = t & 7;
#pragma unroll
    for (int i = 0; i < 2; ++i) {
      int q = (t >> 3) + 32 * i;
#pragma unroll
      for (int j = 0; j < 2; ++j) {
        int c4 = f8 + 8 * j;
        f32x4 o = *(f32x4*)(Osh + q * LDO + c4 * 4);
        *(float4*)(Ob + (size_t)(qb + q) * D_DIM + c4 * 4) =
            make_float4(o.x, o.y, o.z, o.w);
      }
    }
  }
}

// ============================================================================
// FALLBACK (round-3 kernel) — used only if ws_size < WS_NEED.
// ============================================================================
__global__ __launch_bounds__(256, 2)
void fattn_fb(const float* __restrict__ Qg, const float* __restrict__ Kg,
              const float* __restrict__ Vg, const int* __restrict__ Mg,
              float* __restrict__ Og) {
  __shared__ __align__(16) char smem[45056];
  float* Msh = (float*)(smem + 36864);
  float* Osh = (float*)smem;

  const int t = threadIdx.x;
  const int w = t >> 6;
  const int lane = t & 63;
  const int g = lane >> 4;
  const int c = lane & 15;

  const int bh = blockIdx.x & 31;
  const int qt = blockIdx.x >> 5;
  const int qb = qt * 128;

  const float* Qb = Qg + (size_t)bh * SD;
  const float* Kb = Kg + (size_t)bh * SD;
  const float* Vb = Vg + (size_t)bh * SD;
  const int*   Mb = Mg + (size_t)(bh >> 3) * S_LEN;
  float*       Ob = Og + (size_t)bh * SD;

  {
    int4 m0 = *(const int4*)(Mb + 8 * t);
    int4 m1 = *(const int4*)(Mb + 8 * t + 4);
    float4 f0, f1;
    f0.x = (float)(m0.x - 1) * 1e30f; f0.y = (float)(m0.y - 1) * 1e30f;
    f0.z = (float)(m0.z - 1) * 1e30f; f0.w = (float)(m0.w - 1) * 1e30f;
    f1.x = (float)(m1.x - 1) * 1e30f; f1.y = (float)(m1.y - 1) * 1e30f;
    f1.z = (float)(m1.z - 1) * 1e30f; f1.w = (float)(m1.w - 1) * 1e30f;
    *(float4*)(Msh + 8 * t) = f0;
    *(float4*)(Msh + 8 * t + 4) = f1;
  }

  const float qscale = 0.125f * 1.44269504088896340736f;
  half8_t qf[2][2];
#pragma unroll
  for (int h = 0; h < 2; ++h) {
    const float* qp = Qb + (size_t)(qb + 32 * w + 16 * h + c) * D_DIM + 8 * g;
#pragma unroll
    for (int ks = 0; ks < 2; ++ks) {
      float4 lo = *(const float4*)(qp + 32 * ks);
      float4 hi = *(const float4*)(qp + 32 * ks + 4);
      fp16x2 p0 = __builtin_amdgcn_cvt_pkrtz(lo.x * qscale, lo.y * qscale);
      fp16x2 p1 = __builtin_amdgcn_cvt_pkrtz(lo.z * qscale, lo.w * qscale);
      fp16x2 p2 = __builtin_amdgcn_cvt_pkrtz(hi.x * qscale, hi.y * qscale);
      fp16x2 p3 = __builtin_amdgcn_cvt_pkrtz(hi.z * qscale, hi.w * qscale);
      half8_t hh;
      hh[0] = (_Float16)p0[0]; hh[1] = (_Float16)p0[1];
      hh[2] = (_Float16)p1[0]; hh[3] = (_Float16)p1[1];
      hh[4] = (_Float16)p2[0]; hh[5] = (_Float16)p2[1];
      hh[6] = (_Float16)p3[0]; hh[7] = (_Float16)p3[1];
      qf[h][ks] = hh;
    }
  }

  const int krow0 = t >> 4;
  const int kc4   = t & 15;
  const int vp    = t >> 3;
  const int vkpl  = t & 7;

  float4 kr[4];
  float2 vr[8];
  auto prefetch = [&](int kb2) {
#pragma unroll
    for (int it = 0; it < 4; ++it)
      kr[it] = *(const float4*)(Kb + (size_t)(kb2 + krow0 + 16 * it) * D_DIM + kc4 * 4);
#pragma unroll
    for (int kc = 0; kc < 4; ++kc) {
      const float* vpp = Vb + (size_t)(kb2 + 2 * (vkpl + 8 * kc)) * D_DIM + 2 * vp;
      vr[2 * kc]     = *(const float2*)(vpp);
      vr[2 * kc + 1] = *(const float2*)(vpp + D_DIM);
    }
  };
  auto stage = [&](int buf) {
    _Float16* Kd = (_Float16*)(smem + 9216 * buf);
    _Float16* Vd = (_Float16*)(smem + 18432 + 9216 * buf);
#pragma unroll
    for (int it = 0; it < 4; ++it) {
      fp16x2 a  = __builtin_amdgcn_cvt_pkrtz(kr[it].x, kr[it].y);
      fp16x2 b2 = __builtin_amdgcn_cvt_pkrtz(kr[it].z, kr[it].w);
      half4_t h;
      h[0] = (_Float16)a[0]; h[1] = (_Float16)a[1];
      h[2] = (_Float16)b2[0]; h[3] = (_Float16)b2[1];
      *(half4_t*)(Kd + (krow0 + 16 * it) * LDK + kc4 * 4) = h;
    }
#pragma unroll
    for (int kc = 0; kc < 4; ++kc) {
      int kp = vkpl + 8 * kc;
      fp16x2 h0 = __builtin_amdgcn_cvt_pkrtz(vr[2 * kc].x, vr[2 * kc + 1].x);
      fp16x2 h1 = __builtin_amdgcn_cvt_pkrtz(vr[2 * kc].y, vr[2 * kc + 1].y);
      half2_t g0; g0[0] = (_Float16)h0[0]; g0[1] = (_Float16)h0[1];
      half2_t g1; g1[0] = (_Float16)h1[0]; g1[1] = (_Float16)h1[1];
      *(half2_t*)(Vd + (2 * vp) * LDK + 2 * kp) = g0;
      *(half2_t*)(Vd + (2 * vp + 1) * LDK + 2 * kp) = g1;
    }
  };

  f32x4 acc[2][4];
  f32x4 accl[2];
#pragma unroll
  for (int h = 0; h < 2; ++h) {
#pragma unroll
    for (int j = 0; j < 4; ++j) accl[h][j] = 0.f;
#pragma unroll
    for (int i = 0; i < 4; ++i)
#pragma unroll
      for (int j = 0; j < 4; ++j) acc[h][i][j] = 0.f;
  }
  float mrun[2] = {-1e30f, -1e30f};

  half4_t ones4;
  ones4[0] = (_Float16)1.0f; ones4[1] = (_Float16)1.0f;
  ones4[2] = (_Float16)1.0f; ones4[3] = (_Float16)1.0f;

  prefetch(0);
  stage(0);
  prefetch(64);
  __syncthreads();

  for (int kt = 0; kt < 32; ++kt) {
    const int kb = kt * 64;
    const int cur = kt & 1;

    if (kt < 31) stage(cur ^ 1);
    if (kt < 30) prefetch(kb + 128);

    const _Float16* Kc = (const _Float16*)(smem + 9216 * cur);
    const _Float16* Vc = (const _Float16*)(smem + 18432 + 9216 * cur);

    f32x4 sT[2][4];
    __builtin_amdgcn_s_setprio(1);
#pragma unroll
    for (int mt = 0; mt < 4; ++mt) {
      f32x4 z0, z1;
#pragma unroll
      for (int j = 0; j < 4; ++j) { z0[j] = 0.f; z1[j] = 0.f; }
#pragma unroll
      for (int ks = 0; ks < 2; ++ks) {
        half8_t kf = *(half8_t*)(Kc + (16 * mt + c) * LDK + ks * 32 + 8 * g);
        z0 = __builtin_amdgcn_mfma_f32_16x16x32_f16(kf, qf[0][ks], z0, 0, 0, 0);
        z1 = __builtin_amdgcn_mfma_f32_16x16x32_f16(kf, qf[1][ks], z1, 0, 0, 0);
      }
      sT[0][mt] = z0;
      sT[1][mt] = z1;
    }
    __builtin_amdgcn_s_setprio(0);

    half4_t vf[4][4];
#pragma unroll
    for (int dt = 0; dt < 4; ++dt)
#pragma unroll
      for (int kst = 0; kst < 4; ++kst)
        vf[dt][kst] = *(half4_t*)(Vc + (16 * dt + c) * LDK + 16 * kst + 4 * g);

    f32x4 mvf[4];
#pragma unroll
    for (int mt = 0; mt < 4; ++mt)
      mvf[mt] = *(const f32x4*)(Msh + kb + 16 * mt + 4 * g);
#pragma unroll
    for (int h = 0; h < 2; ++h)
#pragma unroll
      for (int mt = 0; mt < 4; ++mt)
#pragma unroll
        for (int r = 0; r < 4; ++r) sT[h][mt][r] += mvf[mt][r];

    float tl[2];
#pragma unroll
    for (int h = 0; h < 2; ++h) {
      float tm0 = fmaxf(fmaxf(sT[h][0][0], sT[h][0][1]),
                        fmaxf(sT[h][0][2], sT[h][0][3]));
      float tm1 = fmaxf(fmaxf(sT[h][1][0], sT[h][1][1]),
                        fmaxf(sT[h][1][2], sT[h][1][3]));
      float tm2 = fmaxf(fmaxf(sT[h][2][0], sT[h][2][1]),
                        fmaxf(sT[h][2][2], sT[h][2][3]));
      float tm3 = fmaxf(fmaxf(sT[h][3][0], sT[h][3][1]),
                        fmaxf(sT[h][3][2], sT[h][3][3]));
      tl[h] = fmaxf(fmaxf(tm0, tm1), fmaxf(tm2, tm3));
    }
    int ok0 = __all(tl[0] <= mrun[0] + THR);
    int ok1 = __all(tl[1] <= mrun[1] + THR);
    if (!(ok0 & ok1)) {
#pragma unroll
      for (int h = 0; h < 2; ++h) {
        float tmax = tl[h];
        tmax = fmaxf(tmax, __shfl_xor(tmax, 16));
        tmax = fmaxf(tmax, __shfl_xor(tmax, 32));
        float mnew = fmaxf(mrun[h], tmax);
        float alpha = __builtin_amdgcn_exp2f(mrun[h] - mnew);
        mrun[h] = mnew;
        accl[h][0] *= alpha; accl[h][1] *= alpha;
        accl[h][2] *= alpha; accl[h][3] *= alpha;
#pragma unroll
        for (int mt = 0; mt < 4; ++mt) {
          acc[h][mt][0] *= alpha; acc[h][mt][1] *= alpha;
          acc[h][mt][2] *= alpha; acc[h][mt][3] *= alpha;
        }
      }
    }

    __builtin_amdgcn_s_setprio(1);
#pragma unroll
    for (int h = 0; h < 2; ++h) {
#pragma unroll
      for (int mt = 0; mt < 4; ++mt) {
        float pv0 = __builtin_amdgcn_exp2f(sT[h][mt][0] - mrun[h]);
        float pv1 = __builtin_amdgcn_exp2f(sT[h][mt][1] - mrun[h]);
        float pv2 = __builtin_amdgcn_exp2f(sT[h][mt][2] - mrun[h]);
        float pv3 = __builtin_amdgcn_exp2f(sT[h][mt][3] - mrun[h]);
        fp16x2 p01 = __builtin_amdgcn_cvt_pkrtz(pv0, pv1);
        fp16x2 p23 = __builtin_amdgcn_cvt_pkrtz(pv2, pv3);
        half4_t pf;
        pf[0] = (_Float16)p01[0]; pf[1] = (_Float16)p01[1];
        pf[2] = (_Float16)p23[0]; pf[3] = (_Float16)p23[1];
        accl[h] = __builtin_amdgcn_mfma_f32_16x16x16f16(ones4, pf, accl[h], 0, 0, 0);
#pragma unroll
        for (int dt = 0; dt < 4; ++dt)
          acc[h][dt] = __builtin_amdgcn_mfma_f32_16x16x16f16(vf[dt][mt], pf,
                                                             acc[h][dt], 0, 0, 0);
      }
    }
    __builtin_amdgcn_s_setprio(0);

    __syncthreads();
  }

#pragma unroll
  for (int h = 0; h < 2; ++h) {
    float linv = 1.f / accl[h][0];
#pragma unroll
    for (int mt = 0; mt < 4; ++mt)
#pragma unroll
      for (int r = 0; r < 4; ++r)
        Osh[(32 * w + 16 * h + c) * LDO + 16 * mt + 4 * g + r] = acc[h][mt][r] * linv;
  }
  __syncthreads();
  {
    int f8 = t & 7;
#pragma unroll
    for (int i = 0; i < 4; ++i) {
      int q = (t >> 3) + 32 * i;
#pragma unroll
      for (int j = 0; j < 2; ++j) {
        int c4 = f8 + 8 * j;
        f32x4 o = *(f32x4*)(Osh + q * LDO + c4 * 4);
        *(float4*)(Ob + (size_t)(qb + q) * D_DIM + c4 * 4) =
            make_float4(o.x, o.y, o.z, o.w);
      }
    }
  }
}

extern "C" void kernel_launch(void* const* d_in, const int* in_sizes, int n_in,
                              void* d_out, int out_size, void* d_ws, size_t ws_size,
                              hipStream_t stream) {
  (void)in_sizes; (void)n_in; (void)out_size;
  const float* Q = (const float*)d_in[0];
  const float* K = (const float*)d_in[1];
  const float* V = (const float*)d_in[2];
  const int*   M = (const int*)d_in[3];
  float* O = (float*)d_out;

  if (ws_size >= WS_NEED && d_ws != nullptr) {
    _Float16* wsK = (_Float16*)d_ws;
    _Float16* wsV = wsK + (size_t)32 * S_LEN * D_DIM;               // +8MB
    _Float16* wsKeep = (_Float16*)((char*)d_ws + 16 * 1024 * 1024); // +16MB
    prep_kernel<<<dim3(2052), dim3(256), 0, stream>>>(K, V, M, wsK, wsV, wsKeep);
    // grid 1024: bh fast (XCD L2 locality), 32 q-tiles of 64 rows slow
    fattn_dma<<<dim3(32 * 32), dim3(256), 0, stream>>>(Q, wsK, wsV, wsKeep, O);
  } else {
    fattn_fb<<<dim3(32 * 16), dim3(256), 0, stream>>>(Q, K, V, M, O);
  }
}